// Round 1
// baseline (928.098 us; speedup 1.0000x reference)
//
#include <hip/hip_runtime.h>

#define NFEAT   128
#define NHID    64
#define NLAYER  3
#define NNODES  50000
#define NEDGES  800000
#define NGRAPHS 512
#define BN_EPS  1e-5f

// ---------------------------------------------------------------- counts
__global__ __launch_bounds__(256) void k_count(const int* __restrict__ batch,
                                               float* __restrict__ cnt) {
    int i = blockIdx.x * 256 + threadIdx.x;
    if (i < NNODES) atomicAdd(&cnt[batch[i]], 1.0f);
}

// ---------------------------------------------------------------- input GEMM: tmp = x @ Wt + bt
__global__ __launch_bounds__(256) void k_gemm_in(const float* __restrict__ x,
                                                 const float* __restrict__ Wt,
                                                 const float* __restrict__ bt,
                                                 float* __restrict__ out) {
    __shared__ float sW[NFEAT * NHID];   // 32 KB
    __shared__ float sx[4 * NFEAT];      // 2 KB
    int tid  = threadIdx.x;
    int base = blockIdx.x * 4;
    for (int i = tid; i < NFEAT * NHID; i += 256) sW[i] = Wt[i];
    for (int i = tid; i < 4 * NFEAT; i += 256) {
        int r = base + i / NFEAT;
        sx[i] = (r < NNODES) ? x[(long long)r * NFEAT + (i % NFEAT)] : 0.f;
    }
    __syncthreads();
    int node = tid >> 6, j = tid & 63;
    int r = base + node;
    if (r >= NNODES) return;
    float acc = bt[j];
    const float* xr = &sx[node * NFEAT];
#pragma unroll
    for (int k = 0; k < NFEAT; ++k) acc += xr[k] * sW[k * NHID + j];
    out[r * NHID + j] = acc;
}

// ---------------------------------------------------------------- BN stats: stats[0:64]=sum, stats[64:128]=sumsq
__global__ __launch_bounds__(256) void k_bnstats(const float* __restrict__ z,
                                                 float* __restrict__ stats) {
    __shared__ float s1[4][64], s2[4][64];
    int tid = threadIdx.x;
    int j = tid & 63, sub = tid >> 6;
    float a1 = 0.f, a2 = 0.f;
    for (int r = blockIdx.x * 4 + sub; r < NNODES; r += gridDim.x * 4) {
        float v = z[r * NHID + j];
        a1 += v;
        a2 += v * v;
    }
    s1[sub][j] = a1;
    s2[sub][j] = a2;
    __syncthreads();
    if (sub == 0) {
        a1 = s1[0][j] + s1[1][j] + s1[2][j] + s1[3][j];
        a2 = s2[0][j] + s2[1][j] + s2[2][j] + s2[3][j];
        atomicAdd(&stats[j], a1);
        atomicAdd(&stats[64 + j], a2);
    }
}

// ---------------------------------------------------------------- BN apply (+optional relu) + pool accumulate
template <int RELU>
__global__ __launch_bounds__(256) void k_bnapply(const float* __restrict__ z,
                                                 const float* __restrict__ stats,
                                                 const float* __restrict__ gamma,
                                                 const float* __restrict__ beta,
                                                 const int* __restrict__ batch,
                                                 float* __restrict__ h,
                                                 float* __restrict__ pool) {
    int idx = blockIdx.x * 256 + threadIdx.x;
    if (idx >= NNODES * NHID) return;
    int j = idx & 63, r = idx >> 6;
    float m = stats[j] * (1.0f / NNODES);
    float v = stats[64 + j] * (1.0f / NNODES) - m * m;
    float val = (z[idx] - m) * rsqrtf(v + BN_EPS) * gamma[j] + beta[j];
    if (RELU) val = fmaxf(val, 0.f);
    h[idx] = val;
    atomicAdd(&pool[batch[r] * NHID + j], val);
}

// ---------------------------------------------------------------- edge scatter: agg[dst] += h[src]
__global__ __launch_bounds__(256) void k_scatter(const float* __restrict__ h,
                                                 const int* __restrict__ ei,
                                                 float* __restrict__ agg) {
    int t = blockIdx.x * 256 + threadIdx.x;
    int e = t >> 6, j = t & 63;
    if (e >= NEDGES) return;
    int src = ei[e];
    int dst = ei[NEDGES + e];
    atomicAdd(&agg[dst * NHID + j], h[src * NHID + j]);
}

// ---------------------------------------------------------------- fused MLP: out = relu((h+agg)@W1+b1)@W2+b2
__global__ __launch_bounds__(256) void k_mlp(const float* __restrict__ h,
                                             const float* __restrict__ agg,
                                             const float* __restrict__ W1,
                                             const float* __restrict__ b1,
                                             const float* __restrict__ W2,
                                             const float* __restrict__ b2,
                                             float* __restrict__ out) {
    __shared__ float sW1[NHID * NHID];   // 16 KB
    __shared__ float sW2[NHID * NHID];   // 16 KB
    __shared__ float sz[4][NHID], st[4][NHID];
    __shared__ float sb1[NHID], sb2[NHID];
    int tid = threadIdx.x;
    for (int i = tid; i < NHID * NHID; i += 256) {
        sW1[i] = W1[i];
        sW2[i] = W2[i];
    }
    if (tid < NHID) {
        sb1[tid] = b1[tid];
        sb2[tid] = b2[tid];
    }
    int node = tid >> 6, j = tid & 63;
    int r = blockIdx.x * 4 + node;
    float zv = (r < NNODES) ? h[r * NHID + j] + agg[r * NHID + j] : 0.f;
    sz[node][j] = zv;
    __syncthreads();
    float acc = sb1[j];
#pragma unroll
    for (int k = 0; k < NHID; ++k) acc += sz[node][k] * sW1[k * NHID + j];
    st[node][j] = fmaxf(acc, 0.f);
    __syncthreads();
    acc = sb2[j];
#pragma unroll
    for (int k = 0; k < NHID; ++k) acc += st[node][k] * sW2[k * NHID + j];
    if (r < NNODES) out[r * NHID + j] = acc;
}

// ---------------------------------------------------------------- finalize: out = pools / max(cnt,1)
__global__ __launch_bounds__(256) void k_final(const float* __restrict__ pools,
                                               const float* __restrict__ cnt,
                                               float* __restrict__ out) {
    int idx = blockIdx.x * 256 + threadIdx.x;
    if (idx >= (NLAYER + 1) * NGRAPHS * NHID) return;
    int g = (idx >> 6) & (NGRAPHS - 1);
    out[idx] = pools[idx] / fmaxf(cnt[g], 1.0f);
}

// ----------------------------------------------------------------
extern "C" void kernel_launch(void* const* d_in, const int* in_sizes, int n_in,
                              void* d_out, int out_size, void* d_ws, size_t ws_size,
                              hipStream_t stream) {
    const float* x     = (const float*)d_in[0];
    const int*   ei    = (const int*)d_in[1];
    const int*   batch = (const int*)d_in[2];
    const float* Wt    = (const float*)d_in[3];
    const float* bt    = (const float*)d_in[4];
    const float* gt    = (const float*)d_in[5];
    const float* bet   = (const float*)d_in[6];
    const float* W1    = (const float*)d_in[7];
    const float* b1    = (const float*)d_in[8];
    const float* W2    = (const float*)d_in[9];
    const float* b2    = (const float*)d_in[10];
    const float* g     = (const float*)d_in[11];
    const float* be    = (const float*)d_in[12];
    float* out = (float*)d_out;

    float* ws    = (float*)d_ws;
    float* tmp   = ws;                         // 50000*64
    float* h     = tmp + NNODES * NHID;        // 50000*64
    float* agg   = h + NNODES * NHID;          // 50000*64
    float* pools = agg + NNODES * NHID;        // 4*512*64
    float* cnt   = pools + (NLAYER + 1) * NGRAPHS * NHID;  // 512
    float* stats = cnt + NGRAPHS;              // 128

    // zero pools + counts (contiguous)
    hipMemsetAsync(pools, 0, ((NLAYER + 1) * NGRAPHS * NHID + NGRAPHS) * sizeof(float), stream);
    k_count<<<(NNODES + 255) / 256, 256, 0, stream>>>(batch, cnt);

    // input transform + BN + pool[0]
    k_gemm_in<<<NNODES / 4, 256, 0, stream>>>(x, Wt, bt, tmp);
    hipMemsetAsync(stats, 0, 128 * sizeof(float), stream);
    k_bnstats<<<200, 256, 0, stream>>>(tmp, stats);
    k_bnapply<0><<<(NNODES * NHID) / 256, 256, 0, stream>>>(tmp, stats, gt, bet, batch, h, pools);

    for (int l = 0; l < NLAYER; ++l) {
        hipMemsetAsync(agg, 0, (size_t)NNODES * NHID * sizeof(float), stream);
        k_scatter<<<(NEDGES * NHID) / 256, 256, 0, stream>>>(h, ei, agg);
        k_mlp<<<NNODES / 4, 256, 0, stream>>>(h, agg, W1 + l * NHID * NHID, b1 + l * NHID,
                                              W2 + l * NHID * NHID, b2 + l * NHID, tmp);
        hipMemsetAsync(stats, 0, 128 * sizeof(float), stream);
        k_bnstats<<<200, 256, 0, stream>>>(tmp, stats);
        k_bnapply<1><<<(NNODES * NHID) / 256, 256, 0, stream>>>(tmp, stats, g + l * NHID, be + l * NHID,
                                                                batch, h, pools + (l + 1) * NGRAPHS * NHID);
    }

    k_final<<<((NLAYER + 1) * NGRAPHS * NHID) / 256, 256, 0, stream>>>(pools, cnt, out);
}

// Round 2
// 685.172 us; speedup vs baseline: 1.3545x; 1.3545x over previous
//
#include <hip/hip_runtime.h>

#define NFEAT   128
#define NHID    64
#define NLAYER  3
#define NNODES  50000
#define NEDGES  800000
#define NGRAPHS 512
#define BN_EPS  1e-5f

// ---------------------------------------------------------------- CSR build: histogram of dst
__global__ __launch_bounds__(256) void k_hist(const int* __restrict__ ei,
                                              int* __restrict__ deg) {
    int e = blockIdx.x * 256 + threadIdx.x;
    if (e < NEDGES) atomicAdd(&deg[ei[NEDGES + e]], 1);
}

// ---------------------------------------------------------------- single-block exclusive scan (50000 -> rowstart[50001])
__global__ __launch_bounds__(1024) void k_scan(const int* __restrict__ deg,
                                               int* __restrict__ rowstart) {
    __shared__ int wsum[16];
    __shared__ int carry;
    int tid = threadIdx.x, lane = tid & 63, w = tid >> 6;
    if (tid == 0) carry = 0;
    __syncthreads();
    for (int base = 0; base < NNODES; base += 1024) {
        int i = base + tid;
        int v = (i < NNODES) ? deg[i] : 0;
        int s = v;
#pragma unroll
        for (int off = 1; off < 64; off <<= 1) {
            int t = __shfl_up(s, off, 64);
            if (lane >= off) s += t;
        }
        if (lane == 63) wsum[w] = s;
        __syncthreads();
        if (tid < 64) {
            int t = (tid < 16) ? wsum[tid] : 0;
#pragma unroll
            for (int off = 1; off < 16; off <<= 1) {
                int u = __shfl_up(t, off, 64);
                if (lane >= off) t += u;
            }
            if (tid < 16) wsum[tid] = t;
        }
        __syncthreads();
        int woff = (w > 0) ? wsum[w - 1] : 0;
        int excl = carry + woff + (s - v);
        if (i < NNODES) rowstart[i] = excl;
        int total = wsum[15];
        __syncthreads();
        if (tid == 0) carry += total;
        __syncthreads();
    }
    if (tid == 0) rowstart[NNODES] = carry;
}

// ---------------------------------------------------------------- fill CSR columns
__global__ __launch_bounds__(256) void k_fill(const int* __restrict__ ei,
                                              const int* __restrict__ rowstart,
                                              int* __restrict__ cursor,
                                              int* __restrict__ col) {
    int e = blockIdx.x * 256 + threadIdx.x;
    if (e >= NEDGES) return;
    int src = ei[e];
    int dst = ei[NEDGES + e];
    int slot = atomicAdd(&cursor[dst], 1);
    col[rowstart[dst] + slot] = src;
}

// ---------------------------------------------------------------- graph start offsets (batch is sorted)
__global__ __launch_bounds__(256) void k_goff(const int* __restrict__ batch,
                                              int* __restrict__ gstart) {
    int gph = blockIdx.x * 256 + threadIdx.x;
    if (gph > NGRAPHS) return;
    if (gph == NGRAPHS) { gstart[NGRAPHS] = NNODES; return; }
    int lo = 0, hi = NNODES;
    while (lo < hi) {
        int mid = (lo + hi) >> 1;
        if (batch[mid] < gph) lo = mid + 1; else hi = mid;
    }
    gstart[gph] = lo;
}

// ---------------------------------------------------------------- input GEMM: tmp = x @ Wt + bt  (16 nodes/block)
__global__ __launch_bounds__(256) void k_gemm_in(const float* __restrict__ x,
                                                 const float* __restrict__ Wt,
                                                 const float* __restrict__ bt,
                                                 float* __restrict__ out) {
    __shared__ float sW[NFEAT * NHID];   // 32 KB
    __shared__ float sx[16 * NFEAT];     // 8 KB
    int tid = threadIdx.x;
    const float4* W4 = (const float4*)Wt;
    float4* sW4 = (float4*)sW;
#pragma unroll
    for (int i = 0; i < NFEAT * NHID / 4 / 256; ++i) sW4[i * 256 + tid] = W4[i * 256 + tid];
    int base = blockIdx.x * 16;
    const float4* x4 = (const float4*)(x + (long long)base * NFEAT);
    float4* sx4 = (float4*)sx;
#pragma unroll
    for (int i = 0; i < 16 * NFEAT / 4 / 256; ++i) sx4[i * 256 + tid] = x4[i * 256 + tid];
    __syncthreads();
    int j = tid & 63, q = tid >> 6;      // q = 0..3, nodes q*4..q*4+3
    float b = bt[j];
    float acc[4] = {b, b, b, b};
    for (int k = 0; k < NFEAT; ++k) {
        float wv = sW[k * NHID + j];
#pragma unroll
        for (int i = 0; i < 4; ++i) acc[i] += sx[(q * 4 + i) * NFEAT + k] * wv;
    }
#pragma unroll
    for (int i = 0; i < 4; ++i) out[(base + q * 4 + i) * NHID + j] = acc[i];
}

// ---------------------------------------------------------------- BN stats into stats[0:64]=sum, [64:128]=sumsq
__global__ __launch_bounds__(256) void k_bnstats(const float* __restrict__ z,
                                                 float* __restrict__ stats) {
    __shared__ float s1[4][64], s2[4][64];
    int tid = threadIdx.x;
    int j = tid & 63, sub = tid >> 6;
    float a1 = 0.f, a2 = 0.f;
    for (int r = blockIdx.x * 4 + sub; r < NNODES; r += gridDim.x * 4) {
        float v = z[r * NHID + j];
        a1 += v;
        a2 += v * v;
    }
    s1[sub][j] = a1;
    s2[sub][j] = a2;
    __syncthreads();
    if (sub == 0) {
        a1 = s1[0][j] + s1[1][j] + s1[2][j] + s1[3][j];
        a2 = s2[0][j] + s2[1][j] + s2[2][j] + s2[3][j];
        atomicAdd(&stats[j], a1);
        atomicAdd(&stats[64 + j], a2);
    }
}

// ---------------------------------------------------------------- BN apply (+optional relu), float4
template <int RELU>
__global__ __launch_bounds__(256) void k_bnapply(const float* __restrict__ z,
                                                 const float* __restrict__ stats,
                                                 const float* __restrict__ gamma,
                                                 const float* __restrict__ beta,
                                                 float* __restrict__ h) {
    int idx = blockIdx.x * 256 + threadIdx.x;       // float4 index
    int j0 = (idx & 15) * 4;
    float4 v4 = ((const float4*)z)[idx];
    float o[4] = {v4.x, v4.y, v4.z, v4.w};
#pragma unroll
    for (int c = 0; c < 4; ++c) {
        int j = j0 + c;
        float m = stats[j] * (1.0f / NNODES);
        float v = stats[64 + j] * (1.0f / NNODES) - m * m;
        float val = (o[c] - m) * rsqrtf(v + BN_EPS) * gamma[j] + beta[j];
        if (RELU) val = fmaxf(val, 0.f);
        o[c] = val;
    }
    ((float4*)h)[idx] = make_float4(o[0], o[1], o[2], o[3]);
}

// ---------------------------------------------------------------- pool per graph (batch sorted, no atomics)
__global__ __launch_bounds__(256) void k_pool(const float* __restrict__ h,
                                              const int* __restrict__ gstart,
                                              float* __restrict__ out) {
    __shared__ float red[4][64];
    int gph = blockIdx.x;
    int j = threadIdx.x & 63, sub = threadIdx.x >> 6;
    int s0 = gstart[gph], e0 = gstart[gph + 1];
    float s = 0.f;
    for (int r = s0 + sub; r < e0; r += 4) s += h[r * NHID + j];
    red[sub][j] = s;
    __syncthreads();
    if (sub == 0) {
        s = red[0][j] + red[1][j] + red[2][j] + red[3][j];
        out[gph * NHID + j] = s / fmaxf((float)(e0 - s0), 1.0f);
    }
}

// ---------------------------------------------------------------- fused gather + MLP: out = relu((h+Σh[src])@W1+b1)@W2+b2
__global__ __launch_bounds__(256) void k_mlp(const float* __restrict__ h,
                                             const int* __restrict__ rowstart,
                                             const int* __restrict__ col,
                                             const float* __restrict__ W1,
                                             const float* __restrict__ b1,
                                             const float* __restrict__ W2,
                                             const float* __restrict__ b2,
                                             float* __restrict__ out) {
    __shared__ float sW1[NHID * NHID];   // 16 KB
    __shared__ float sW2[NHID * NHID];   // 16 KB
    __shared__ float sz[4][NHID], st[4][NHID];
    int tid = threadIdx.x;
    const float4* W14 = (const float4*)W1;
    const float4* W24 = (const float4*)W2;
    float4* s14 = (float4*)sW1;
    float4* s24 = (float4*)sW2;
#pragma unroll
    for (int i = 0; i < 4; ++i) {
        s14[i * 256 + tid] = W14[i * 256 + tid];
        s24[i * 256 + tid] = W24[i * 256 + tid];
    }
    int node = tid >> 6, j = tid & 63;
    int r = blockIdx.x * 4 + node;
    // gather: z = h[r] + sum over incident edges
    float z = h[r * NHID + j];
    int s = rowstart[r];
    int deg = rowstart[r + 1] - s;
    for (int base = 0; base < deg; base += 64) {
        int m = min(64, deg - base);
        int idx = (base + j < deg) ? col[s + base + j] : 0;
        for (int d = 0; d < m; ++d) {
            int src = __shfl(idx, d, 64);
            z += h[src * NHID + j];
        }
    }
    sz[node][j] = z;
    __syncthreads();
    float acc = b1[j];
#pragma unroll
    for (int k = 0; k < NHID; ++k) acc += sz[node][k] * sW1[k * NHID + j];
    st[node][j] = fmaxf(acc, 0.f);
    __syncthreads();
    acc = b2[j];
#pragma unroll
    for (int k = 0; k < NHID; ++k) acc += st[node][k] * sW2[k * NHID + j];
    out[r * NHID + j] = acc;
}

// ----------------------------------------------------------------
extern "C" void kernel_launch(void* const* d_in, const int* in_sizes, int n_in,
                              void* d_out, int out_size, void* d_ws, size_t ws_size,
                              hipStream_t stream) {
    const float* x     = (const float*)d_in[0];
    const int*   ei    = (const int*)d_in[1];
    const int*   batch = (const int*)d_in[2];
    const float* Wt    = (const float*)d_in[3];
    const float* bt    = (const float*)d_in[4];
    const float* gt    = (const float*)d_in[5];
    const float* bet   = (const float*)d_in[6];
    const float* W1    = (const float*)d_in[7];
    const float* b1    = (const float*)d_in[8];
    const float* W2    = (const float*)d_in[9];
    const float* b2    = (const float*)d_in[10];
    const float* g     = (const float*)d_in[11];
    const float* be    = (const float*)d_in[12];
    float* out = (float*)d_out;

    float* ws   = (float*)d_ws;
    float* tmp  = ws;                          // 50000*64 f32
    float* h    = tmp + NNODES * NHID;         // 50000*64 f32
    // int region (after 2*3.2M floats)
    int* ibase    = (int*)(h + NNODES * NHID);
    int* deg      = ibase;                     // 50000
    int* cursor   = deg + NNODES;              // 50000
    float* stats  = (float*)(cursor + NNODES); // 4 stages x 128 f32 = 512
    int* rowstart = (int*)(stats + 4 * 128);   // 50001
    int* col      = rowstart + NNODES + 1;     // 800000
    int* gstart   = col + NEDGES;              // 513

    // one memset clears deg, cursor, and all 4 stage-stats (contiguous)
    hipMemsetAsync(deg, 0, (2 * NNODES + 4 * 128) * sizeof(int), stream);

    // CSR build (once; reused by all 3 layers) + graph offsets
    k_hist<<<NEDGES / 256, 256, 0, stream>>>(ei, deg);
    k_scan<<<1, 1024, 0, stream>>>(deg, rowstart);
    k_fill<<<NEDGES / 256, 256, 0, stream>>>(ei, rowstart, cursor, col);
    k_goff<<<3, 256, 0, stream>>>(batch, gstart);

    // input transform + BN + pool[0]
    k_gemm_in<<<NNODES / 16, 256, 0, stream>>>(x, Wt, bt, tmp);
    k_bnstats<<<512, 256, 0, stream>>>(tmp, stats);
    k_bnapply<0><<<NNODES * NHID / 4 / 256, 256, 0, stream>>>(tmp, stats, gt, bet, h);
    k_pool<<<NGRAPHS, 256, 0, stream>>>(h, gstart, out);

    for (int l = 0; l < NLAYER; ++l) {
        float* st_l = stats + (l + 1) * 128;
        k_mlp<<<NNODES / 4, 256, 0, stream>>>(h, rowstart, col,
                                              W1 + l * NHID * NHID, b1 + l * NHID,
                                              W2 + l * NHID * NHID, b2 + l * NHID, tmp);
        k_bnstats<<<512, 256, 0, stream>>>(tmp, st_l);
        k_bnapply<1><<<NNODES * NHID / 4 / 256, 256, 0, stream>>>(tmp, st_l, g + l * NHID, be + l * NHID, h);
        k_pool<<<NGRAPHS, 256, 0, stream>>>(h, gstart, out + (l + 1) * NGRAPHS * NHID);
    }
}